// Round 1
// baseline (8617.287 us; speedup 1.0000x reference)
//
#include <hip/hip_runtime.h>
#include <hip/hip_bf16.h>
#include <stdint.h>

#define BB   128
#define TT   512
#define DIN  512
#define HH   1024
#define GG   4096     // 4*H
#define KTOT 1536     // DIN + HH
#define OUTD 256

typedef __bf16 bf16x8 __attribute__((ext_vector_type(8)));
typedef float f32x4 __attribute__((ext_vector_type(4)));
typedef unsigned short u16x8 __attribute__((ext_vector_type(8)));

__device__ __forceinline__ unsigned short f2bf(float f) {
  unsigned int u = __float_as_uint(f);
  u += 0x7fffu + ((u >> 16) & 1u);          // RNE to bf16
  return (unsigned short)(u >> 16);
}
__device__ __forceinline__ float bf2f(unsigned short s) {
  return __uint_as_float(((unsigned int)s) << 16);
}

// ---- prep: Wc[g][k] bf16 = concat(W_ih[g][:], W_hh[g][:]) along k ----------
__global__ __launch_bounds__(256) void prep_wcat(const float* __restrict__ Wih,
                                                 const float* __restrict__ Whh,
                                                 unsigned short* __restrict__ Wc) {
  const int KC = KTOT / 8;                  // 192 chunks of 8 per row
  size_t n = (size_t)GG * KC;
  for (size_t idx = (size_t)blockIdx.x * blockDim.x + threadIdx.x; idx < n;
       idx += (size_t)gridDim.x * blockDim.x) {
    int g = (int)(idx / KC);
    int k = (int)(idx % KC) * 8;
    const float* src = (k < DIN) ? (Wih + (size_t)g * DIN + k)
                                 : (Whh + (size_t)g * HH + (k - DIN));
    float4 a = *(const float4*)src;
    float4 b = *(const float4*)(src + 4);
    u16x8 o;
    o[0] = f2bf(a.x); o[1] = f2bf(a.y); o[2] = f2bf(a.z); o[3] = f2bf(a.w);
    o[4] = f2bf(b.x); o[5] = f2bf(b.y); o[6] = f2bf(b.z); o[7] = f2bf(b.w);
    *(u16x8*)(Wc + idx * 8) = o;
  }
}

__global__ __launch_bounds__(256) void prep_bias(const float* __restrict__ a,
                                                 const float* __restrict__ b,
                                                 float* __restrict__ o) {
  int i = blockIdx.x * blockDim.x + threadIdx.x;
  if (i < GG) o[i] = a[i] + b[i];
}

// ---- one LSTM time step (reversed order handled via rt) --------------------
// grid 256: (4 batch tiles of 32) x (64 h-dim blocks of 16); 4 waves = gates i,f,g,o
__global__ __launch_bounds__(256, 1) void lstm_step(
    const float* __restrict__ x,            // [B][T][DIN] f32
    const unsigned short* __restrict__ Wc,  // [GG][KTOT] bf16
    const float* __restrict__ bias,         // [GG] (b_ih + b_hh)
    float* __restrict__ cst,                // [B][H] f32 cell state
    unsigned short* __restrict__ hbuf,      // [2][B][H] bf16 ping-pong
    int t) {
  __shared__ __align__(16) unsigned char Als[32 * 3072];  // 96KB A-tile, swizzled
  __shared__ float gl[4][32][16];                         // gates staging, 8KB

  const int bid = blockIdx.x;
  const int bi = bid >> 6;                   // batch tile 0..3
  const int j = (bid & 7) * 8 + ((bid >> 3) & 7);  // h-dim block 0..63 (XCD-clustered)
  const int tid = threadIdx.x;
  const int s = tid >> 6;                    // wave = gate section (i,f,g,o)
  const int lane = tid & 63;
  const int l16 = lane & 15;
  const int lk = lane >> 4;                  // k-group 0..3

  const int rt = (TT - 1) - t;
  const unsigned short* hprev = hbuf + (size_t)(t & 1) * (BB * HH);
  unsigned short* hnext = hbuf + (size_t)((t + 1) & 1) * (BB * HH);
  const int b0 = bi * 32;

  // ---- stage A tile: 32 rows (batch) x 1536 bf16 (x | h), XOR-swizzled ----
  for (int ch = tid; ch < 32 * 192; ch += 256) {
    int row = ch / 192;
    int col16 = ch % 192;
    int kbf = col16 * 8;
    u16x8 v;
    if (kbf < DIN) {
      const float* src = x + ((size_t)(b0 + row) * TT + rt) * DIN + kbf;
      float4 xa = *(const float4*)src;
      float4 xb = *(const float4*)(src + 4);
      v[0] = f2bf(xa.x); v[1] = f2bf(xa.y); v[2] = f2bf(xa.z); v[3] = f2bf(xa.w);
      v[4] = f2bf(xb.x); v[5] = f2bf(xb.y); v[6] = f2bf(xb.z); v[7] = f2bf(xb.w);
    } else {
      v = *(const u16x8*)(hprev + (size_t)(b0 + row) * HH + (kbf - DIN));
    }
    int byteoff = (row * 3072 + col16 * 16) ^ ((row & 7) << 4);
    *(u16x8*)(Als + byteoff) = v;
  }
  __syncthreads();

  // ---- MFMA: gates[32 batch][16 dims] for section s over K=1536 -----------
  const unsigned short* wrow = Wc + (size_t)(s * HH + j * 16 + l16) * KTOT;
  f32x4 accA0 = {0.f, 0.f, 0.f, 0.f}, accA1 = {0.f, 0.f, 0.f, 0.f};
  f32x4 accB0 = {0.f, 0.f, 0.f, 0.f}, accB1 = {0.f, 0.f, 0.f, 0.f};
  const int base0 = l16 * 3072 + lk * 16;          // m-frag 0, row = l16
  const int base1 = (16 + l16) * 3072 + lk * 16;   // m-frag 1
  const int sw = (l16 & 7) << 4;
#pragma unroll 6
  for (int kk = 0; kk < 48; kk += 2) {
    bf16x8 bw0 = *(const bf16x8*)(wrow + kk * 32 + lk * 8);
    bf16x8 a00 = *(const bf16x8*)(Als + ((base0 + kk * 64) ^ sw));
    bf16x8 a10 = *(const bf16x8*)(Als + ((base1 + kk * 64) ^ sw));
    accA0 = __builtin_amdgcn_mfma_f32_16x16x32_bf16(a00, bw0, accA0, 0, 0, 0);
    accA1 = __builtin_amdgcn_mfma_f32_16x16x32_bf16(a10, bw0, accA1, 0, 0, 0);
    bf16x8 bw1 = *(const bf16x8*)(wrow + (kk + 1) * 32 + lk * 8);
    bf16x8 a01 = *(const bf16x8*)(Als + ((base0 + (kk + 1) * 64) ^ sw));
    bf16x8 a11 = *(const bf16x8*)(Als + ((base1 + (kk + 1) * 64) ^ sw));
    accB0 = __builtin_amdgcn_mfma_f32_16x16x32_bf16(a01, bw1, accB0, 0, 0, 0);
    accB1 = __builtin_amdgcn_mfma_f32_16x16x32_bf16(a11, bw1, accB1, 0, 0, 0);
  }
  f32x4 acc0 = accA0 + accB0;
  f32x4 acc1 = accA1 + accB1;

  // D layout: row (batch) = lk*4 + r, col (gate dim) = l16   [guide m89/m91]
#pragma unroll
  for (int r = 0; r < 4; ++r) {
    gl[s][lk * 4 + r][l16] = acc0[r];
    gl[s][16 + lk * 4 + r][l16] = acc1[r];
  }
  __syncthreads();

  // ---- elementwise LSTM cell update: 512 (b,k) pairs, 2 per thread --------
  for (int p = tid; p < 512; p += 256) {
    int m = p >> 4;
    int kd = p & 15;
    int kglob = j * 16 + kd;
    float gi = gl[0][m][kd] + bias[0 * HH + kglob];
    float gf = gl[1][m][kd] + bias[1 * HH + kglob];
    float gg = gl[2][m][kd] + bias[2 * HH + kglob];
    float go = gl[3][m][kd] + bias[3 * HH + kglob];
    float si = 1.f / (1.f + __expf(-gi));
    float sf = 1.f / (1.f + __expf(-gf));
    float tg = tanhf(gg);
    float so = 1.f / (1.f + __expf(-go));
    size_t ci = (size_t)(b0 + m) * HH + kglob;
    float cv = sf * cst[ci] + si * tg;
    cst[ci] = cv;
    hnext[ci] = f2bf(so * tanhf(cv));
  }
}

// ---- out = h_final @ W_out^T + b_out (f32) --------------------------------
__global__ __launch_bounds__(256) void out_proj(const unsigned short* __restrict__ hfin,
                                                const float* __restrict__ Wout,
                                                const float* __restrict__ bout,
                                                float* __restrict__ out) {
  __shared__ float hs[HH];
  int b = blockIdx.x;
  int tid = threadIdx.x;
  for (int k = tid; k < HH; k += 256) hs[k] = bf2f(hfin[(size_t)b * HH + k]);
  __syncthreads();
  const float* wr = Wout + (size_t)tid * HH;
  float acc = bout[tid];
#pragma unroll 4
  for (int k = 0; k < HH; k += 4) {
    float4 wv = *(const float4*)(wr + k);
    acc += hs[k] * wv.x + hs[k + 1] * wv.y + hs[k + 2] * wv.z + hs[k + 3] * wv.w;
  }
  out[(size_t)b * OUTD + tid] = acc;
}

extern "C" void kernel_launch(void* const* d_in, const int* in_sizes, int n_in,
                              void* d_out, int out_size, void* d_ws, size_t ws_size,
                              hipStream_t stream) {
  const float* x    = (const float*)d_in[0];
  const float* Wih  = (const float*)d_in[1];
  const float* Whh  = (const float*)d_in[2];
  const float* bih  = (const float*)d_in[3];
  const float* bhh  = (const float*)d_in[4];
  const float* Wout = (const float*)d_in[5];
  const float* bout = (const float*)d_in[6];
  float* out = (float*)d_out;

  // ws layout (all offsets 256B-aligned), total ~13.7 MB
  uint8_t* w = (uint8_t*)d_ws;
  unsigned short* Wc   = (unsigned short*)(w);             // 4096*1536*2 = 12,582,912
  float* bias          = (float*)(w + 12582912);           // 16,384
  float* cst           = (float*)(w + 12599296);           // 524,288
  unsigned short* hbuf = (unsigned short*)(w + 13123584);  // 2*128*1024*2 = 524,288

  hipMemsetAsync(cst, 0, (size_t)BB * HH * sizeof(float), stream);
  hipMemsetAsync(hbuf, 0, (size_t)BB * HH * sizeof(unsigned short), stream);
  prep_wcat<<<1024, 256, 0, stream>>>(Wih, Whh, Wc);
  prep_bias<<<GG / 256, 256, 0, stream>>>(bih, bhh, bias);
  for (int t = 0; t < TT; ++t)
    lstm_step<<<256, 256, 0, stream>>>(x, Wc, bias, cst, hbuf, t);
  out_proj<<<BB, 256, 0, stream>>>(hbuf, Wout, bout, out);
}

// Round 2
// 7732.140 us; speedup vs baseline: 1.1145x; 1.1145x over previous
//
#include <hip/hip_runtime.h>
#include <hip/hip_bf16.h>
#include <stdint.h>

#define BB   128
#define TT   512
#define DIN  512
#define HH   1024
#define GG   4096
#define KTOT 1536
#define OUTD 256
#define NWG  256
#define NTHR 512

typedef __bf16 bf16x8 __attribute__((ext_vector_type(8)));
typedef float f32x4 __attribute__((ext_vector_type(4)));
typedef unsigned short u16x8 __attribute__((ext_vector_type(8)));

__device__ __forceinline__ unsigned short f2bf(float f) {
  unsigned int u = __float_as_uint(f);
  u += 0x7fffu + ((u >> 16) & 1u);
  return (unsigned short)(u >> 16);
}
__device__ __forceinline__ float bf2f(unsigned short s) {
  return __uint_as_float(((unsigned int)s) << 16);
}

// ---- prep: Wc[g][k] bf16 = concat(W_ih[g][:], W_hh[g][:]) along k ----------
__global__ __launch_bounds__(256) void prep_wcat(const float* __restrict__ Wih,
                                                 const float* __restrict__ Whh,
                                                 unsigned short* __restrict__ Wc) {
  const int KC = KTOT / 8;
  size_t n = (size_t)GG * KC;
  for (size_t idx = (size_t)blockIdx.x * blockDim.x + threadIdx.x; idx < n;
       idx += (size_t)gridDim.x * blockDim.x) {
    int g = (int)(idx / KC);
    int k = (int)(idx % KC) * 8;
    const float* src = (k < DIN) ? (Wih + (size_t)g * DIN + k)
                                 : (Whh + (size_t)g * HH + (k - DIN));
    float4 a = *(const float4*)src;
    float4 b = *(const float4*)(src + 4);
    u16x8 o;
    o[0] = f2bf(a.x); o[1] = f2bf(a.y); o[2] = f2bf(a.z); o[3] = f2bf(a.w);
    o[4] = f2bf(b.x); o[5] = f2bf(b.y); o[6] = f2bf(b.z); o[7] = f2bf(b.w);
    *(u16x8*)(Wc + idx * 8) = o;
  }
}

// ---- persistent LSTM: 256 WGs x 512 thr, weights in VGPRs, 512 steps -------
// WG = (batch tile m: 32 rows, dim group n: 16 h-dims). Wave wv = K-octant.
__global__ __launch_bounds__(NTHR, 2) void lstm_persist(
    const float* __restrict__ x,            // [B][T][DIN] f32
    const unsigned short* __restrict__ Wc,  // [GG][KTOT] bf16
    const float* __restrict__ bih,
    const float* __restrict__ bhh,
    unsigned short* __restrict__ hbuf,      // [2][B][H] bf16 ping-pong
    unsigned int* __restrict__ bar) {       // 4 group counters (stride 16)
  __shared__ __align__(16) unsigned char LS[98304];  // A-tile 96KB; accs alias [0,64K)

  const int bid = blockIdx.x;
  const int m = (bid & 7) >> 1;                    // batch tile 0..3 (XCD-paired)
  const int n = ((bid >> 3) << 1) | (bid & 1);     // dim group 0..63
  const int tid = threadIdx.x;
  const int wv = tid >> 6;                         // wave = K-octant 0..7
  const int lane = tid & 63;
  const int l16 = lane & 15;
  const int lk = lane >> 4;
  const int b0 = m * 32;

  // ---- preload B-fragments for all 512 steps: wreg[kk][nt] ---------------
  // gate-row = nt*H + n*16 + l16 ; k = wv*192 + kk*32 + lk*8 + e
  bf16x8 wreg[6][4];
#pragma unroll
  for (int nt = 0; nt < 4; ++nt) {
    const unsigned short* wrow =
        Wc + (size_t)(nt * HH + n * 16 + l16) * KTOT + wv * 192 + lk * 8;
#pragma unroll
    for (int kk = 0; kk < 6; ++kk) wreg[kk][nt] = *(const bf16x8*)(wrow + kk * 32);
  }

  // ---- per-thread cell element (ml = batch-local 0..31, dd = dim 0..15) ---
  const int ml = tid >> 4, dd = tid & 15;
  const int kg = n * 16 + dd;
  const float bi_ = bih[0 * HH + kg] + bhh[0 * HH + kg];
  const float bf_ = bih[1 * HH + kg] + bhh[1 * HH + kg];
  const float bg_ = bih[2 * HH + kg] + bhh[2 * HH + kg];
  const float bo_ = bih[3 * HH + kg] + bhh[3 * HH + kg];
  float cst = 0.f;
  const size_t hidx = (size_t)(b0 + ml) * HH + kg;
  // gather base: frag value (row=ml&15 -> lane'=((ml&15)>>2)*16+dd, r=ml&3), mt=ml>>4
  float* gbase = (float*)LS + (((ml >> 4) * 64 + ((ml & 15) >> 2) * 16 + dd) * 4 + (ml & 3));

  const int swz = (l16 & 7) << 4;

#pragma unroll 1
  for (int t = 0; t < TT; ++t) {
    const unsigned short* hprev = hbuf + (size_t)(t & 1) * (BB * HH);
    unsigned short* hnext = hbuf + (size_t)((t + 1) & 1) * (BB * HH);
    const int rt = (TT - 1) - t;

    // ---- stage A tile: 32 rows x 1536 bf16 (x|h), XOR-swizzled ----------
#pragma unroll
    for (int it = 0; it < 12; ++it) {
      int ch = tid + it * NTHR;
      int row = ch / 192;
      int col16 = ch % 192;
      int kbf = col16 * 8;
      u16x8 v;
      if (kbf < DIN) {
        const float* src = x + ((size_t)(b0 + row) * TT + rt) * DIN + kbf;
        float4 xa = *(const float4*)src;
        float4 xb = *(const float4*)(src + 4);
        v[0] = f2bf(xa.x); v[1] = f2bf(xa.y); v[2] = f2bf(xa.z); v[3] = f2bf(xa.w);
        v[4] = f2bf(xb.x); v[5] = f2bf(xb.y); v[6] = f2bf(xb.z); v[7] = f2bf(xb.w);
      } else {
        v = *(const u16x8*)(hprev + (size_t)(b0 + row) * HH + (kbf - DIN));
      }
      int byteoff = (row * 3072 + col16 * 16) ^ ((row & 7) << 4);
      *(u16x8*)(LS + byteoff) = v;
    }
    __syncthreads();

    // ---- MFMA: this wave's K-octant (6 k-steps) x 4 gate sections x 2 m ---
    f32x4 acc[4][2];
#pragma unroll
    for (int nt = 0; nt < 4; ++nt) {
      acc[nt][0] = (f32x4){0.f, 0.f, 0.f, 0.f};
      acc[nt][1] = (f32x4){0.f, 0.f, 0.f, 0.f};
    }
#pragma unroll
    for (int kk = 0; kk < 6; ++kk) {
      int co = (wv * 6 + kk) * 64 + lk * 16;
      bf16x8 a0 = *(const bf16x8*)(LS + ((l16 * 3072 + co) ^ swz));
      bf16x8 a1 = *(const bf16x8*)(LS + (((16 + l16) * 3072 + co) ^ swz));
#pragma unroll
      for (int nt = 0; nt < 4; ++nt) {
        acc[nt][0] = __builtin_amdgcn_mfma_f32_16x16x32_bf16(a0, wreg[kk][nt], acc[nt][0], 0, 0, 0);
        acc[nt][1] = __builtin_amdgcn_mfma_f32_16x16x32_bf16(a1, wreg[kk][nt], acc[nt][1], 0, 0, 0);
      }
    }
    __syncthreads();  // A-tile dead; reuse LS[0,64K) for K-partials

    // ---- write K-partials in fragment order (coalesced f32x4) -----------
#pragma unroll
    for (int nt = 0; nt < 4; ++nt) {
      *(f32x4*)(LS + (((wv * 4 + nt) * 2 + 0) * 64 + lane) * 16) = acc[nt][0];
      *(f32x4*)(LS + (((wv * 4 + nt) * 2 + 1) * 64 + lane) * 16) = acc[nt][1];
    }
    __syncthreads();

    // ---- elementwise cell update (1 elem/thread), gates = sum of 8 octants
    float g0 = 0.f, g1 = 0.f, g2 = 0.f, g3 = 0.f;
#pragma unroll
    for (int kt = 0; kt < 8; ++kt) {
      g0 += gbase[(kt * 4 + 0) * 512];
      g1 += gbase[(kt * 4 + 1) * 512];
      g2 += gbase[(kt * 4 + 2) * 512];
      g3 += gbase[(kt * 4 + 3) * 512];
    }
    float gi = g0 + bi_, gf = g1 + bf_, gg = g2 + bg_, go = g3 + bo_;
    float si = 1.f / (1.f + __expf(-gi));
    float sf = 1.f / (1.f + __expf(-gf));
    float tg = tanhf(gg);
    float so = 1.f / (1.f + __expf(-go));
    cst = sf * cst + si * tg;
    hnext[hidx] = f2bf(so * tanhf(cst));

    // ---- group barrier (64 WGs sharing batch tile m), monotonic ----------
    __syncthreads();  // all h stores drained (vmcnt0 before s_barrier)
    if (tid == 0) {
      __hip_atomic_fetch_add(&bar[m * 16], 1u, __ATOMIC_RELEASE, __HIP_MEMORY_SCOPE_AGENT);
      unsigned tgt = 64u * (unsigned)(t + 1);
      while (__hip_atomic_load(&bar[m * 16], __ATOMIC_ACQUIRE, __HIP_MEMORY_SCOPE_AGENT) < tgt)
        __builtin_amdgcn_s_sleep(1);
    }
    __syncthreads();
  }
}

// ---- out = h_final @ W_out^T + b_out (f32) --------------------------------
__global__ __launch_bounds__(256) void out_proj(const unsigned short* __restrict__ hfin,
                                                const float* __restrict__ Wout,
                                                const float* __restrict__ bout,
                                                float* __restrict__ out) {
  __shared__ float hs[HH];
  int b = blockIdx.x;
  int tid = threadIdx.x;
  for (int k = tid; k < HH; k += 256) hs[k] = bf2f(hfin[(size_t)b * HH + k]);
  __syncthreads();
  const float* wr = Wout + (size_t)tid * HH;
  float acc = bout[tid];
#pragma unroll 4
  for (int k = 0; k < HH; k += 4) {
    float4 wv = *(const float4*)(wr + k);
    acc += hs[k] * wv.x + hs[k + 1] * wv.y + hs[k + 2] * wv.z + hs[k + 3] * wv.w;
  }
  out[(size_t)b * OUTD + tid] = acc;
}

extern "C" void kernel_launch(void* const* d_in, const int* in_sizes, int n_in,
                              void* d_out, int out_size, void* d_ws, size_t ws_size,
                              hipStream_t stream) {
  const float* x    = (const float*)d_in[0];
  const float* Wih  = (const float*)d_in[1];
  const float* Whh  = (const float*)d_in[2];
  const float* bih  = (const float*)d_in[3];
  const float* bhh  = (const float*)d_in[4];
  const float* Wout = (const float*)d_in[5];
  const float* bout = (const float*)d_in[6];
  float* out = (float*)d_out;

  uint8_t* w = (uint8_t*)d_ws;
  unsigned short* Wc   = (unsigned short*)(w);              // 12,582,912 B
  unsigned short* hbuf = (unsigned short*)(w + 12582912);   // 524,288 B
  unsigned int*   bar  = (unsigned int*)(w + 13107200);     // 256 B

  // h0 = 0 and barrier counters = 0 (captured -> reset on every replay)
  hipMemsetAsync(hbuf, 0, (size_t)BB * HH * sizeof(unsigned short), stream);
  hipMemsetAsync(bar, 0, 256, stream);
  prep_wcat<<<1024, 256, 0, stream>>>(Wih, Whh, Wc);

  void* args[] = {(void*)&x, (void*)&Wc, (void*)&bih, (void*)&bhh,
                  (void*)&hbuf, (void*)&bar};
  hipLaunchCooperativeKernel((const void*)lstm_persist, dim3(NWG), dim3(NTHR),
                             args, 0, stream);

  // final h is hbuf[0] (TT even)
  out_proj<<<BB, 256, 0, stream>>>(hbuf, Wout, bout, out);
}

// Round 3
// 5280.964 us; speedup vs baseline: 1.6318x; 1.4642x over previous
//
#include <hip/hip_runtime.h>
#include <hip/hip_bf16.h>
#include <stdint.h>

#define BB   128
#define TT   512
#define DIN  512
#define HH   1024
#define GG   4096
#define KTOT 1536
#define OUTD 256
#define NWG  256
#define NTHR 512
#define PB   98304   // partials base in LDS

typedef __bf16 bf16x8 __attribute__((ext_vector_type(8)));
typedef float f32x4 __attribute__((ext_vector_type(4)));
typedef unsigned short u16x8 __attribute__((ext_vector_type(8)));

__device__ __forceinline__ unsigned short f2bf(float f) {
  unsigned int u = __float_as_uint(f);
  u += 0x7fffu + ((u >> 16) & 1u);
  return (unsigned short)(u >> 16);
}
__device__ __forceinline__ float bf2f(unsigned short s) {
  return __uint_as_float(((unsigned int)s) << 16);
}

// ---- prep: Wc[g][k] bf16 = concat(W_ih[g][:], W_hh[g][:]) along k ----------
__global__ __launch_bounds__(256) void prep_wcat(const float* __restrict__ Wih,
                                                 const float* __restrict__ Whh,
                                                 unsigned short* __restrict__ Wc) {
  const int KC = KTOT / 8;
  size_t n = (size_t)GG * KC;
  for (size_t idx = (size_t)blockIdx.x * blockDim.x + threadIdx.x; idx < n;
       idx += (size_t)gridDim.x * blockDim.x) {
    int g = (int)(idx / KC);
    int k = (int)(idx % KC) * 8;
    const float* src = (k < DIN) ? (Wih + (size_t)g * DIN + k)
                                 : (Whh + (size_t)g * HH + (k - DIN));
    float4 a = *(const float4*)src;
    float4 b = *(const float4*)(src + 4);
    u16x8 o;
    o[0] = f2bf(a.x); o[1] = f2bf(a.y); o[2] = f2bf(a.z); o[3] = f2bf(a.w);
    o[4] = f2bf(b.x); o[5] = f2bf(b.y); o[6] = f2bf(b.z); o[7] = f2bf(b.w);
    *(u16x8*)(Wc + idx * 8) = o;
  }
}

// ---- persistent LSTM: 256 WGs x 512 thr, weights in VGPRs, 512 steps -------
__global__ __launch_bounds__(NTHR, 1) void lstm_persist(
    const float* __restrict__ x,            // [B][T][DIN] f32
    const unsigned short* __restrict__ Wc,  // [GG][KTOT] bf16
    const float* __restrict__ bih,
    const float* __restrict__ bhh,
    unsigned short* __restrict__ hbuf,      // [2][B][H] bf16 ping-pong
    unsigned int* __restrict__ barw) {      // [4][64] per-WG arrival words
  __shared__ __align__(16) unsigned char LS[131072];  // A 96K | partials 32K

  const int bid = blockIdx.x;
  const int m = (bid & 7) >> 1;                    // batch tile 0..3 (2 XCDs/group)
  const int n = ((bid >> 3) << 1) | (bid & 1);     // dim group 0..63
  const int slot = ((bid >> 3) << 1) | (bid & 1);  // arrival slot 0..63
  const int tid = threadIdx.x;
  const int wv = tid >> 6;                         // wave = K-octant 0..7
  const int lane = tid & 63;
  const int l16 = lane & 15;
  const int lk = lane >> 4;
  const int b0 = m * 32;

  // ---- preload B-fragments (all 512 steps): 96 VGPRs ----------------------
  bf16x8 wreg[6][4];
#pragma unroll
  for (int nt = 0; nt < 4; ++nt) {
    const unsigned short* wrow =
        Wc + (size_t)(nt * HH + n * 16 + l16) * KTOT + wv * 192 + lk * 8;
#pragma unroll
    for (int kk = 0; kk < 6; ++kk) wreg[kk][nt] = *(const bf16x8*)(wrow + kk * 32);
  }

  // ---- per-thread cell element -------------------------------------------
  const int ml = tid >> 4, dd = tid & 15;
  const int kg = n * 16 + dd;
  const float bi_ = bih[0 * HH + kg] + bhh[0 * HH + kg];
  const float bf_ = bih[1 * HH + kg] + bhh[1 * HH + kg];
  const float bg_ = bih[2 * HH + kg] + bhh[2 * HH + kg];
  const float bo_ = bih[3 * HH + kg] + bhh[3 * HH + kg];
  float cst = 0.f;
  const size_t hidx = (size_t)(b0 + ml) * HH + kg;
  const int mt = ml >> 4;
  const int fragoff = (((ml & 15) >> 2) * 16 + dd) * 4 + (ml & 3);
  const float* gb = (const float*)(LS + PB) + fragoff;

  const int swz = (l16 & 7) << 4;
  unsigned int* grpw = barw + m * 64;

  // ---- prologue: stage x-part of A for t=0 -------------------------------
  {
    const int rt0 = TT - 1;
#pragma unroll
    for (int it = 0; it < 4; ++it) {
      int ch = tid + it * NTHR;            // 0..2047
      int row = ch >> 6, col16 = ch & 63;
      const float* src = x + ((size_t)(b0 + row) * TT + rt0) * DIN + col16 * 8;
      float4 xa = *(const float4*)src;
      float4 xb = *(const float4*)(src + 4);
      u16x8 v;
      v[0] = f2bf(xa.x); v[1] = f2bf(xa.y); v[2] = f2bf(xa.z); v[3] = f2bf(xa.w);
      v[4] = f2bf(xb.x); v[5] = f2bf(xb.y); v[6] = f2bf(xb.z); v[7] = f2bf(xb.w);
      *(u16x8*)(LS + ((row * 3072 + col16 * 16) ^ ((row & 7) << 4))) = v;
    }
  }

#pragma unroll 1
  for (int t = 0; t < TT; ++t) {
    const unsigned short* hprev = hbuf + (size_t)(t & 1) * (BB * HH);
    unsigned short* hnext = hbuf + (size_t)((t + 1) & 1) * (BB * HH);

    // ---- stage h-part of A (cols 512..1535) ------------------------------
#pragma unroll
    for (int it = 0; it < 8; ++it) {
      int ch = tid + it * NTHR;            // 0..4095
      int row = ch >> 7, c = ch & 127;
      u16x8 v = *(const u16x8*)(hprev + (size_t)(b0 + row) * HH + c * 8);
      int byteoff = ((row * 3072 + (64 + c) * 16) ^ ((row & 7) << 4));
      *(u16x8*)(LS + byteoff) = v;
    }
    __syncthreads();

    // ---- MFMA over this wave's K-octant ----------------------------------
    f32x4 acc[4][2];
#pragma unroll
    for (int nt = 0; nt < 4; ++nt) {
      acc[nt][0] = (f32x4){0.f, 0.f, 0.f, 0.f};
      acc[nt][1] = (f32x4){0.f, 0.f, 0.f, 0.f};
    }
#pragma unroll
    for (int kk = 0; kk < 6; ++kk) {
      int co = (wv * 6 + kk) * 64 + lk * 16;
      bf16x8 a0 = *(const bf16x8*)(LS + ((l16 * 3072 + co) ^ swz));
      bf16x8 a1 = *(const bf16x8*)(LS + (((16 + l16) * 3072 + co) ^ swz));
#pragma unroll
      for (int nt = 0; nt < 4; ++nt) {
        acc[nt][0] = __builtin_amdgcn_mfma_f32_16x16x32_bf16(a0, wreg[kk][nt], acc[nt][0], 0, 0, 0);
        acc[nt][1] = __builtin_amdgcn_mfma_f32_16x16x32_bf16(a1, wreg[kk][nt], acc[nt][1], 0, 0, 0);
      }
    }
    __syncthreads();

    // ---- cross-wave K-reduction in LDS: 2 rounds (waves 0-3 then 4-7) ----
    if (wv < 4) {
#pragma unroll
      for (int nt = 0; nt < 4; ++nt) {
        *(f32x4*)(LS + PB + ((((wv & 3) * 4 + nt) * 2 + 0) * 64 + lane) * 16) = acc[nt][0];
        *(f32x4*)(LS + PB + ((((wv & 3) * 4 + nt) * 2 + 1) * 64 + lane) * 16) = acc[nt][1];
      }
    }
    __syncthreads();
    if (wv >= 4) {
#pragma unroll
      for (int nt = 0; nt < 4; ++nt) {
#pragma unroll
        for (int mm = 0; mm < 2; ++mm) {
          f32x4* p = (f32x4*)(LS + PB + ((((wv & 3) * 4 + nt) * 2 + mm) * 64 + lane) * 16);
          *p = *p + acc[nt][mm];
        }
      }
    }
    __syncthreads();

    // ---- elementwise cell update (1 elem/thread) -------------------------
    float g0 = 0.f, g1 = 0.f, g2 = 0.f, g3 = 0.f;
#pragma unroll
    for (int kt = 0; kt < 4; ++kt) {
      g0 += gb[((kt * 4 + 0) * 2 + mt) * 256];
      g1 += gb[((kt * 4 + 1) * 2 + mt) * 256];
      g2 += gb[((kt * 4 + 2) * 2 + mt) * 256];
      g3 += gb[((kt * 4 + 3) * 2 + mt) * 256];
    }
    float gi = g0 + bi_, gf = g1 + bf_, gg = g2 + bg_, go = g3 + bo_;
    float si = 1.f / (1.f + __expf(-gi));
    float sf = 1.f / (1.f + __expf(-gf));
    float tg = tanhf(gg);
    float so = 1.f / (1.f + __expf(-go));
    cst = sf * cst + si * tg;
    hnext[hidx] = f2bf(so * tanhf(cst));

    if (t == TT - 1) break;

    __syncthreads();  // all waves' h stores drained to L2

    // ---- arrival: one release store per WG (wbl2 -> h visible at LLC) ----
    if (tid == 0)
      __hip_atomic_store(&grpw[slot], (unsigned)(t + 1), __ATOMIC_RELEASE,
                         __HIP_MEMORY_SCOPE_AGENT);

    // ---- overlap: stage x-part of A for t+1 (independent of h) -----------
    {
      const int rt2 = TT - 2 - t;
#pragma unroll
      for (int it = 0; it < 4; ++it) {
        int ch = tid + it * NTHR;
        int row = ch >> 6, col16 = ch & 63;
        const float* src = x + ((size_t)(b0 + row) * TT + rt2) * DIN + col16 * 8;
        float4 xa = *(const float4*)src;
        float4 xb = *(const float4*)(src + 4);
        u16x8 v;
        v[0] = f2bf(xa.x); v[1] = f2bf(xa.y); v[2] = f2bf(xa.z); v[3] = f2bf(xa.w);
        v[4] = f2bf(xb.x); v[5] = f2bf(xb.y); v[6] = f2bf(xb.z); v[7] = f2bf(xb.w);
        *(u16x8*)(LS + ((row * 3072 + col16 * 16) ^ ((row & 7) << 4))) = v;
      }
    }

    // ---- wait: wave0 lanes poll 64 arrival words (relaxed; no L2 inv) ----
    if (wv == 0) {
      const unsigned tgt = (unsigned)(t + 1);
      int it = 0;
      while (true) {
        unsigned v = __hip_atomic_load(&grpw[lane], __ATOMIC_RELAXED,
                                       __HIP_MEMORY_SCOPE_AGENT);
        if (__all(v >= tgt)) break;
        __builtin_amdgcn_s_sleep(2);
        if ((++it & 15) == 0) {
          v = __hip_atomic_load(&grpw[lane], __ATOMIC_ACQUIRE,
                                __HIP_MEMORY_SCOPE_AGENT);
          if (__all(v >= tgt)) break;
        }
      }
      __builtin_amdgcn_fence(__ATOMIC_ACQUIRE, "agent");  // one L2 inv/step
    }
    __syncthreads();
  }
}

// ---- out = h_final @ W_out^T + b_out (f32) --------------------------------
__global__ __launch_bounds__(256) void out_proj(const unsigned short* __restrict__ hfin,
                                                const float* __restrict__ Wout,
                                                const float* __restrict__ bout,
                                                float* __restrict__ out) {
  __shared__ float hs[HH];
  int b = blockIdx.x;
  int tid = threadIdx.x;
  for (int k = tid; k < HH; k += 256) hs[k] = bf2f(hfin[(size_t)b * HH + k]);
  __syncthreads();
  const float* wr = Wout + (size_t)tid * HH;
  float acc = bout[tid];
#pragma unroll 4
  for (int k = 0; k < HH; k += 4) {
    float4 wv = *(const float4*)(wr + k);
    acc += hs[k] * wv.x + hs[k + 1] * wv.y + hs[k + 2] * wv.z + hs[k + 3] * wv.w;
  }
  out[(size_t)b * OUTD + tid] = acc;
}

extern "C" void kernel_launch(void* const* d_in, const int* in_sizes, int n_in,
                              void* d_out, int out_size, void* d_ws, size_t ws_size,
                              hipStream_t stream) {
  const float* x    = (const float*)d_in[0];
  const float* Wih  = (const float*)d_in[1];
  const float* Whh  = (const float*)d_in[2];
  const float* bih  = (const float*)d_in[3];
  const float* bhh  = (const float*)d_in[4];
  const float* Wout = (const float*)d_in[5];
  const float* bout = (const float*)d_in[6];
  float* out = (float*)d_out;

  uint8_t* w = (uint8_t*)d_ws;
  unsigned short* Wc   = (unsigned short*)(w);              // 12,582,912 B
  unsigned short* hbuf = (unsigned short*)(w + 12582912);   // 524,288 B
  unsigned int*   barw = (unsigned int*)(w + 13107200);     // 1,024 B

  hipMemsetAsync(hbuf, 0, (size_t)BB * HH * sizeof(unsigned short), stream);
  hipMemsetAsync(barw, 0, 1024, stream);
  prep_wcat<<<1024, 256, 0, stream>>>(Wih, Whh, Wc);

  void* args[] = {(void*)&x, (void*)&Wc, (void*)&bih, (void*)&bhh,
                  (void*)&hbuf, (void*)&barw};
  hipLaunchCooperativeKernel((const void*)lstm_persist, dim3(NWG), dim3(NTHR),
                             args, 0, stream);

  out_proj<<<BB, 256, 0, stream>>>(hbuf, Wout, bout, out);
}

// Round 4
// 2961.898 us; speedup vs baseline: 2.9094x; 1.7830x over previous
//
#include <hip/hip_runtime.h>
#include <hip/hip_bf16.h>
#include <stdint.h>

#define BB   128
#define TT   512
#define DIN  512
#define HH   1024
#define GG   4096
#define KTOT 1536
#define OUTD 256
#define NWG  256
#define NTHR 512
#define PB   98304   // partials base in LDS

typedef __bf16 bf16x8 __attribute__((ext_vector_type(8)));
typedef float f32x4 __attribute__((ext_vector_type(4)));
typedef unsigned short u16x8 __attribute__((ext_vector_type(8)));
typedef unsigned long long u64;

__device__ __forceinline__ unsigned short f2bf(float f) {
  unsigned int u = __float_as_uint(f);
  u += 0x7fffu + ((u >> 16) & 1u);
  return (unsigned short)(u >> 16);
}
__device__ __forceinline__ float bf2f(unsigned short s) {
  return __uint_as_float(((unsigned int)s) << 16);
}

// ---- prep: Wc[g][k] bf16 = concat(W_ih[g][:], W_hh[g][:]) along k ----------
__global__ __launch_bounds__(256) void prep_wcat(const float* __restrict__ Wih,
                                                 const float* __restrict__ Whh,
                                                 unsigned short* __restrict__ Wc) {
  const int KC = KTOT / 8;
  size_t n = (size_t)GG * KC;
  for (size_t idx = (size_t)blockIdx.x * blockDim.x + threadIdx.x; idx < n;
       idx += (size_t)gridDim.x * blockDim.x) {
    int g = (int)(idx / KC);
    int k = (int)(idx % KC) * 8;
    const float* src = (k < DIN) ? (Wih + (size_t)g * DIN + k)
                                 : (Whh + (size_t)g * HH + (k - DIN));
    float4 a = *(const float4*)src;
    float4 b = *(const float4*)(src + 4);
    u16x8 o;
    o[0] = f2bf(a.x); o[1] = f2bf(a.y); o[2] = f2bf(a.z); o[3] = f2bf(a.w);
    o[4] = f2bf(b.x); o[5] = f2bf(b.y); o[6] = f2bf(b.z); o[7] = f2bf(b.w);
    *(u16x8*)(Wc + idx * 8) = o;
  }
}

// ---- persistent LSTM: 256 WGs x 512 thr, weights in VGPRs, 512 steps -------
// K split per wave wv: x cols [wv*64, +64), h cols [512 + wv*128, +128).
__global__ __launch_bounds__(NTHR, 1) void lstm_persist(
    const float* __restrict__ x,            // [B][T][DIN] f32
    const unsigned short* __restrict__ Wc,  // [GG][KTOT] bf16
    const float* __restrict__ bih,
    const float* __restrict__ bhh,
    unsigned short* __restrict__ hbuf,      // [2][B][H] bf16 ping-pong
    unsigned int* __restrict__ barw) {      // [4][64] per-WG arrival words
  __shared__ __align__(16) unsigned char LS[131072];  // A 96K | partials 32K

  const int bid = blockIdx.x;
  const int m = (bid & 7) >> 1;                    // batch tile 0..3
  const int n = ((bid >> 3) << 1) | (bid & 1);     // dim group 0..63
  const int tid = threadIdx.x;
  const int wv = tid >> 6;
  const int lane = tid & 63;
  const int l16 = lane & 15;
  const int lk = lane >> 4;
  const int b0 = m * 32;

  // ---- preload B-fragments: slots 0-1 = x-part, 2-5 = h-part --------------
  bf16x8 wreg[6][4];
#pragma unroll
  for (int nt = 0; nt < 4; ++nt) {
    const unsigned short* wrow = Wc + (size_t)(nt * HH + n * 16 + l16) * KTOT;
#pragma unroll
    for (int kk = 0; kk < 2; ++kk)
      wreg[kk][nt] = *(const bf16x8*)(wrow + wv * 64 + kk * 32 + lk * 8);
#pragma unroll
    for (int kk = 2; kk < 6; ++kk)
      wreg[kk][nt] = *(const bf16x8*)(wrow + 512 + wv * 128 + (kk - 2) * 32 + lk * 8);
  }

  // ---- per-thread cell element -------------------------------------------
  const int ml = tid >> 4, dd = tid & 15;
  const int kg = n * 16 + dd;
  const float bi_ = bih[0 * HH + kg] + bhh[0 * HH + kg];
  const float bf_ = bih[1 * HH + kg] + bhh[1 * HH + kg];
  const float bg_ = bih[2 * HH + kg] + bhh[2 * HH + kg];
  const float bo_ = bih[3 * HH + kg] + bhh[3 * HH + kg];
  float cst = 0.f;
  const size_t hidx = (size_t)(b0 + ml) * HH + kg;
  const int mt = ml >> 4;
  const int fragoff = (((ml & 15) >> 2) * 16 + dd) * 4 + (ml & 3);
  const float* gb = (const float*)(LS + PB) + fragoff;

  const int swz = (l16 & 7) << 4;
  unsigned int* grpw = barw + m * 64;
  const int slot = n;

  f32x4 acc[4][2];

  // ---- stage x-part of A for step t (cols 0..511) -------------------------
  auto stage_x = [&](int rt) {
#pragma unroll
    for (int it = 0; it < 4; ++it) {
      int ch = tid + it * NTHR;
      int row = ch >> 6, col16 = ch & 63;
      const float* src = x + ((size_t)(b0 + row) * TT + rt) * DIN + col16 * 8;
      float4 xa = *(const float4*)src;
      float4 xb = *(const float4*)(src + 4);
      u16x8 v;
      v[0] = f2bf(xa.x); v[1] = f2bf(xa.y); v[2] = f2bf(xa.z); v[3] = f2bf(xa.w);
      v[4] = f2bf(xb.x); v[5] = f2bf(xb.y); v[6] = f2bf(xb.z); v[7] = f2bf(xb.w);
      *(u16x8*)(LS + ((row * 3072 + col16 * 16) ^ ((row & 7) << 4))) = v;
    }
  };

  // ---- x-part MFMA: init acc, 2 kk-steps ---------------------------------
  auto xmfma = [&]() {
#pragma unroll
    for (int nt = 0; nt < 4; ++nt) {
      acc[nt][0] = (f32x4){0.f, 0.f, 0.f, 0.f};
      acc[nt][1] = (f32x4){0.f, 0.f, 0.f, 0.f};
    }
#pragma unroll
    for (int kk = 0; kk < 2; ++kk) {
      int co = wv * 128 + kk * 64 + lk * 16;
      bf16x8 a0 = *(const bf16x8*)(LS + ((l16 * 3072 + co) ^ swz));
      bf16x8 a1 = *(const bf16x8*)(LS + (((16 + l16) * 3072 + co) ^ swz));
#pragma unroll
      for (int nt = 0; nt < 4; ++nt) {
        acc[nt][0] = __builtin_amdgcn_mfma_f32_16x16x32_bf16(a0, wreg[kk][nt], acc[nt][0], 0, 0, 0);
        acc[nt][1] = __builtin_amdgcn_mfma_f32_16x16x32_bf16(a1, wreg[kk][nt], acc[nt][1], 0, 0, 0);
      }
    }
  };

  // prologue: x(t=0) staged + x-MFMA done before loop
  stage_x(TT - 1);
  __syncthreads();
  xmfma();

#pragma unroll 1
  for (int t = 0; t < TT; ++t) {
    const unsigned short* hprev = hbuf + (size_t)(t & 1) * (BB * HH);
    unsigned short* hnext = hbuf + (size_t)((t + 1) & 1) * (BB * HH);

    // ---- stage h-part of A (cols 512..1535) via LLC-coherent loads -------
#pragma unroll
    for (int it = 0; it < 8; ++it) {
      int ch = tid + it * NTHR;
      int row = ch >> 7, c = ch & 127;
      const u64* src = (const u64*)(hprev + (size_t)(b0 + row) * HH + c * 8);
      u64 lo = __hip_atomic_load(src, __ATOMIC_RELAXED, __HIP_MEMORY_SCOPE_AGENT);
      u64 hi = __hip_atomic_load(src + 1, __ATOMIC_RELAXED, __HIP_MEMORY_SCOPE_AGENT);
      int byteoff = ((row * 3072 + (64 + c) * 16) ^ ((row & 7) << 4));
      *(u64*)(LS + byteoff) = lo;
      *(u64*)(LS + byteoff + 8) = hi;
    }
    __syncthreads();

    // ---- h-part MFMA: 4 kk-steps, accumulates onto x-part ----------------
#pragma unroll
    for (int kk = 0; kk < 4; ++kk) {
      int co = 1024 + wv * 256 + kk * 64 + lk * 16;
      bf16x8 a0 = *(const bf16x8*)(LS + ((l16 * 3072 + co) ^ swz));
      bf16x8 a1 = *(const bf16x8*)(LS + (((16 + l16) * 3072 + co) ^ swz));
#pragma unroll
      for (int nt = 0; nt < 4; ++nt) {
        acc[nt][0] = __builtin_amdgcn_mfma_f32_16x16x32_bf16(a0, wreg[kk + 2][nt], acc[nt][0], 0, 0, 0);
        acc[nt][1] = __builtin_amdgcn_mfma_f32_16x16x32_bf16(a1, wreg[kk + 2][nt], acc[nt][1], 0, 0, 0);
      }
    }
    __syncthreads();

    // ---- cross-wave K-reduction in LDS (2 rounds) ------------------------
    if (wv < 4) {
#pragma unroll
      for (int nt = 0; nt < 4; ++nt) {
        *(f32x4*)(LS + PB + ((((wv & 3) * 4 + nt) * 2 + 0) * 64 + lane) * 16) = acc[nt][0];
        *(f32x4*)(LS + PB + ((((wv & 3) * 4 + nt) * 2 + 1) * 64 + lane) * 16) = acc[nt][1];
      }
    }
    __syncthreads();
    if (wv >= 4) {
#pragma unroll
      for (int nt = 0; nt < 4; ++nt) {
#pragma unroll
        for (int mm = 0; mm < 2; ++mm) {
          f32x4* p = (f32x4*)(LS + PB + ((((wv & 3) * 4 + nt) * 2 + mm) * 64 + lane) * 16);
          *p = *p + acc[nt][mm];
        }
      }
    }
    __syncthreads();

    // ---- elementwise cell update (1 elem/thread) -------------------------
    float g0 = 0.f, g1 = 0.f, g2 = 0.f, g3 = 0.f;
#pragma unroll
    for (int kt = 0; kt < 4; ++kt) {
      g0 += gb[((kt * 4 + 0) * 2 + mt) * 256];
      g1 += gb[((kt * 4 + 1) * 2 + mt) * 256];
      g2 += gb[((kt * 4 + 2) * 2 + mt) * 256];
      g3 += gb[((kt * 4 + 3) * 2 + mt) * 256];
    }
    float gi = g0 + bi_, gf = g1 + bf_, gg = g2 + bg_, go = g3 + bo_;
    float si = 1.f / (1.f + __expf(-gi));
    float sf = 1.f / (1.f + __expf(-gf));
    float tg = tanhf(gg);
    float so = 1.f / (1.f + __expf(-go));
    cst = sf * cst + si * tg;

    // pack (dd, dd^1) pair into a dword; even-dd lanes write through to LLC
    unsigned hv = (unsigned)f2bf(so * tanhf(cst));
    unsigned other = (unsigned)__shfl_xor((int)hv, 1);
    if ((dd & 1) == 0) {
      unsigned dword = hv | (other << 16);
      __hip_atomic_store((unsigned*)(hnext + hidx), dword, __ATOMIC_RELAXED,
                         __HIP_MEMORY_SCOPE_AGENT);
    }

    if (t == TT - 1) break;

    __syncthreads();  // vmcnt(0): h write-throughs completed at LLC

    // ---- arrival flag (no fence, no wbl2) --------------------------------
    if (tid == 0)
      __hip_atomic_store(&grpw[slot], (unsigned)(t + 1), __ATOMIC_RELAXED,
                         __HIP_MEMORY_SCOPE_AGENT);

    // ---- wait shadow: stage x(t+1) + x-part MFMA(t+1) --------------------
    stage_x(TT - 2 - t);
    __syncthreads();
    xmfma();

    // ---- poll 64 arrival words (relaxed; acquire only as backstop) -------
    if (wv == 0) {
      const unsigned tgt = (unsigned)(t + 1);
      int it = 0;
      while (true) {
        unsigned v = __hip_atomic_load(&grpw[lane], __ATOMIC_RELAXED,
                                       __HIP_MEMORY_SCOPE_AGENT);
        if (__all(v >= tgt)) break;
        __builtin_amdgcn_s_sleep(2);
        if ((++it & 15) == 0) {
          v = __hip_atomic_load(&grpw[lane], __ATOMIC_ACQUIRE,
                                __HIP_MEMORY_SCOPE_AGENT);
          if (__all(v >= tgt)) break;
        }
      }
    }
    __syncthreads();
  }
}

// ---- out = h_final @ W_out^T + b_out (f32) --------------------------------
__global__ __launch_bounds__(256) void out_proj(const unsigned short* __restrict__ hfin,
                                                const float* __restrict__ Wout,
                                                const float* __restrict__ bout,
                                                float* __restrict__ out) {
  __shared__ float hs[HH];
  int b = blockIdx.x;
  int tid = threadIdx.x;
  for (int k = tid; k < HH; k += 256) hs[k] = bf2f(hfin[(size_t)b * HH + k]);
  __syncthreads();
  const float* wr = Wout + (size_t)tid * HH;
  float acc = bout[tid];
#pragma unroll 4
  for (int k = 0; k < HH; k += 4) {
    float4 wv = *(const float4*)(wr + k);
    acc += hs[k] * wv.x + hs[k + 1] * wv.y + hs[k + 2] * wv.z + hs[k + 3] * wv.w;
  }
  out[(size_t)b * OUTD + tid] = acc;
}

extern "C" void kernel_launch(void* const* d_in, const int* in_sizes, int n_in,
                              void* d_out, int out_size, void* d_ws, size_t ws_size,
                              hipStream_t stream) {
  const float* x    = (const float*)d_in[0];
  const float* Wih  = (const float*)d_in[1];
  const float* Whh  = (const float*)d_in[2];
  const float* bih  = (const float*)d_in[3];
  const float* bhh  = (const float*)d_in[4];
  const float* Wout = (const float*)d_in[5];
  const float* bout = (const float*)d_in[6];
  float* out = (float*)d_out;

  uint8_t* w = (uint8_t*)d_ws;
  unsigned short* Wc   = (unsigned short*)(w);              // 12,582,912 B
  unsigned short* hbuf = (unsigned short*)(w + 12582912);   // 524,288 B
  unsigned int*   barw = (unsigned int*)(w + 13107200);     // 1,024 B

  hipMemsetAsync(hbuf, 0, (size_t)BB * HH * sizeof(unsigned short), stream);
  hipMemsetAsync(barw, 0, 1024, stream);
  prep_wcat<<<1024, 256, 0, stream>>>(Wih, Whh, Wc);

  void* args[] = {(void*)&x, (void*)&Wc, (void*)&bih, (void*)&bhh,
                  (void*)&hbuf, (void*)&barw};
  hipLaunchCooperativeKernel((const void*)lstm_persist, dim3(NWG), dim3(NTHR),
                             args, 0, stream);

  out_proj<<<BB, 256, 0, stream>>>(hbuf, Wout, bout, out);
}

// Round 5
// 2737.899 us; speedup vs baseline: 3.1474x; 1.0818x over previous
//
#include <hip/hip_runtime.h>
#include <hip/hip_bf16.h>
#include <stdint.h>

#define BB   128
#define TT   512
#define DIN  512
#define HH   1024
#define GG   4096
#define KTOT 1536
#define OUTD 256
#define NWG  256
#define NTHR 512

typedef __bf16 bf16x8 __attribute__((ext_vector_type(8)));
typedef float f32x4 __attribute__((ext_vector_type(4)));
typedef unsigned short u16x8 __attribute__((ext_vector_type(8)));
typedef unsigned long long u64;

__device__ __forceinline__ unsigned short f2bf(float f) {
  unsigned int u = __float_as_uint(f);
  u += 0x7fffu + ((u >> 16) & 1u);
  return (unsigned short)(u >> 16);
}
__device__ __forceinline__ float bf2f(unsigned short s) {
  return __uint_as_float(((unsigned int)s) << 16);
}

// ---- prep: Wc[g][k] bf16 = concat(W_ih[g][:], W_hh[g][:]) along k ----------
__global__ __launch_bounds__(256) void prep_wcat(const float* __restrict__ Wih,
                                                 const float* __restrict__ Whh,
                                                 unsigned short* __restrict__ Wc) {
  const int KC = KTOT / 8;
  size_t n = (size_t)GG * KC;
  for (size_t idx = (size_t)blockIdx.x * blockDim.x + threadIdx.x; idx < n;
       idx += (size_t)gridDim.x * blockDim.x) {
    int g = (int)(idx / KC);
    int k = (int)(idx % KC) * 8;
    const float* src = (k < DIN) ? (Wih + (size_t)g * DIN + k)
                                 : (Whh + (size_t)g * HH + (k - DIN));
    float4 a = *(const float4*)src;
    float4 b = *(const float4*)(src + 4);
    u16x8 o;
    o[0] = f2bf(a.x); o[1] = f2bf(a.y); o[2] = f2bf(a.z); o[3] = f2bf(a.w);
    o[4] = f2bf(b.x); o[5] = f2bf(b.y); o[6] = f2bf(b.z); o[7] = f2bf(b.w);
    *(u16x8*)(Wc + idx * 8) = o;
  }
}

// ---- persistent LSTM -------------------------------------------------------
// h ring: hfr[4 slot][4 m][128 kc][32 row][8 bf16]  (fragment order, sc1)
//   slot stride 131072 ushorts, m stride 32768 ushorts.
// flags[4 m][64 n]: WG (m,n) stores t+1 after publishing h(t+1).
__global__ __launch_bounds__(NTHR, 2) void lstm_persist(
    const float* __restrict__ x,            // [B][T][DIN] f32
    const unsigned short* __restrict__ Wc,  // [GG][KTOT] bf16
    const float* __restrict__ bih,
    const float* __restrict__ bhh,
    unsigned short* __restrict__ hfr,
    unsigned int* __restrict__ flags) {
  __shared__ __align__(16) unsigned char LS[65536];  // 8-wave partials only

  const int bid = blockIdx.x;
  const int m = (bid & 7) >> 1;                    // batch tile 0..3
  const int n = ((bid >> 3) << 1) | (bid & 1);     // dim group 0..63
  const int tid = threadIdx.x;
  const int wv = tid >> 6;                         // wave = K-octant
  const int lane = tid & 63;
  const int l16 = lane & 15;
  const int lk = lane >> 4;
  const int b0 = m * 32;

  // ---- preload B-fragments: slots 0-1 = x-part (K 64/wave), 2-5 = h-part --
  bf16x8 wreg[6][4];
#pragma unroll
  for (int nt = 0; nt < 4; ++nt) {
    const unsigned short* wrow = Wc + (size_t)(nt * HH + n * 16 + l16) * KTOT;
#pragma unroll
    for (int kk = 0; kk < 2; ++kk)
      wreg[kk][nt] = *(const bf16x8*)(wrow + wv * 64 + kk * 32 + lk * 8);
#pragma unroll
    for (int kk = 2; kk < 6; ++kk)
      wreg[kk][nt] = *(const bf16x8*)(wrow + 512 + wv * 128 + (kk - 2) * 32 + lk * 8);
  }

  // ---- per-thread cell element -------------------------------------------
  const int ml = tid >> 4, dd = tid & 15;
  const int kg = n * 16 + dd;
  const float bi_ = bih[0 * HH + kg] + bhh[0 * HH + kg];
  const float bf_ = bih[1 * HH + kg] + bhh[1 * HH + kg];
  const float bg_ = bih[2 * HH + kg] + bhh[2 * HH + kg];
  const float bo_ = bih[3 * HH + kg] + bhh[3 * HH + kg];
  float cst = 0.f;
  // gather const: mf*256 + lane'*4 + r
  const int gbo = (ml >> 4) * 256 + (((ml & 15) >> 2) * 16 + dd) * 4 + (ml & 3);
  // h-store ushort index within (slot,m): chunk (n*2 + dd/8), row ml, elem dd%8
  const unsigned hso = (unsigned)(((n * 2 + (dd >> 3)) * 32 + ml) * 8 + (dd & 7));
  unsigned int* grpf = flags + m * 64;
  const int myflag = wv * 8 + (lane & 7);

  f32x4 acc[4][2];
  bf16x8 xaf[2][2];

  // ---- x fragment loads (direct from global f32, L2-hot) ------------------
  auto xload = [&](int rt) {
#pragma unroll
    for (int kk = 0; kk < 2; ++kk)
#pragma unroll
      for (int mf = 0; mf < 2; ++mf) {
        const float* src = x + ((size_t)(b0 + mf * 16 + l16) * TT + rt) * DIN +
                           wv * 64 + kk * 32 + lk * 8;
        float4 a = *(const float4*)src;
        float4 b = *(const float4*)(src + 4);
        u16x8 v;
        v[0] = f2bf(a.x); v[1] = f2bf(a.y); v[2] = f2bf(a.z); v[3] = f2bf(a.w);
        v[4] = f2bf(b.x); v[5] = f2bf(b.y); v[6] = f2bf(b.z); v[7] = f2bf(b.w);
        xaf[kk][mf] = (bf16x8)v;
      }
  };
  auto xmfma = [&]() {
#pragma unroll
    for (int nt = 0; nt < 4; ++nt) {
      acc[nt][0] = (f32x4){0.f, 0.f, 0.f, 0.f};
      acc[nt][1] = (f32x4){0.f, 0.f, 0.f, 0.f};
    }
#pragma unroll
    for (int kk = 0; kk < 2; ++kk)
#pragma unroll
      for (int mf = 0; mf < 2; ++mf)
#pragma unroll
        for (int nt = 0; nt < 4; ++nt)
          acc[nt][mf] = __builtin_amdgcn_mfma_f32_16x16x32_bf16(
              xaf[kk][mf], wreg[kk][nt], acc[nt][mf], 0, 0, 0);
  };

  xload(TT - 1);
  xmfma();

#pragma unroll 1
  for (int t = 0;; ) {
    // ---- per-wave poll: my 8 producers have published h(t) ---------------
    {
      const unsigned tgt = (unsigned)t;
      int it = 0;
      while (true) {
        unsigned v = __hip_atomic_load(&grpf[myflag], __ATOMIC_RELAXED,
                                       __HIP_MEMORY_SCOPE_AGENT);
        if (__all(v >= tgt)) break;
        __builtin_amdgcn_s_sleep(1);
        if ((++it & 15) == 0) {
          v = __hip_atomic_load(&grpf[myflag], __ATOMIC_ACQUIRE,
                                __HIP_MEMORY_SCOPE_AGENT);
          if (__all(v >= tgt)) break;
        }
      }
    }

    // ---- h fragment loads (sc1, LLC) + h-part MFMA -----------------------
    {
      const unsigned short* hs = hfr + (size_t)(t & 3) * 131072 + m * 32768;
#pragma unroll
      for (int kk = 0; kk < 4; ++kk) {
        int kc = wv * 16 + kk * 4 + lk;
#pragma unroll
        for (int mf = 0; mf < 2; ++mf) {
          const u64* p = (const u64*)(hs + ((size_t)kc * 32 + mf * 16 + l16) * 8);
          u64 lo = __hip_atomic_load(p, __ATOMIC_RELAXED, __HIP_MEMORY_SCOPE_AGENT);
          u64 hi = __hip_atomic_load(p + 1, __ATOMIC_RELAXED, __HIP_MEMORY_SCOPE_AGENT);
          union { u64 q[2]; bf16x8 v; } c;
          c.q[0] = lo; c.q[1] = hi;
#pragma unroll
          for (int nt = 0; nt < 4; ++nt)
            acc[nt][mf] = __builtin_amdgcn_mfma_f32_16x16x32_bf16(
                c.v, wreg[kk + 2][nt], acc[nt][mf], 0, 0, 0);
        }
      }
    }

    // ---- all 8 waves write partials to distinct LDS slots ----------------
#pragma unroll
    for (int nt = 0; nt < 4; ++nt)
#pragma unroll
      for (int mf = 0; mf < 2; ++mf)
        *(f32x4*)(LS + ((((wv * 4 + nt) * 2 + mf) * 64) + lane) * 16) = acc[nt][mf];
    __syncthreads();  // S1

    // ---- gather 8-way K-partials + cell update (1 elem/thread) -----------
    float g0 = 0.f, g1 = 0.f, g2 = 0.f, g3 = 0.f;
    const float* P = (const float*)LS;
#pragma unroll
    for (int w = 0; w < 8; ++w) {
      g0 += P[gbo + (w * 4 + 0) * 512];
      g1 += P[gbo + (w * 4 + 1) * 512];
      g2 += P[gbo + (w * 4 + 2) * 512];
      g3 += P[gbo + (w * 4 + 3) * 512];
    }
    float gi = g0 + bi_, gf = g1 + bf_, gg = g2 + bg_, go = g3 + bo_;
    float si = 1.f / (1.f + __expf(-gi));
    float sf = 1.f / (1.f + __expf(-gf));
    float tg = tanhf(gg);
    float so = 1.f / (1.f + __expf(-go));
    cst = sf * cst + si * tg;

    // ---- publish h(t+1) in fragment order (paired dword, sc1) ------------
    unsigned hv = (unsigned)f2bf(so * tanhf(cst));
    unsigned other = (unsigned)__shfl_xor((int)hv, 1);
    if (!(dd & 1)) {
      unsigned dword = hv | (other << 16);
      unsigned short* dst = hfr + (size_t)((t + 1) & 3) * 131072 + m * 32768 + hso;
      __hip_atomic_store((unsigned*)dst, dword, __ATOMIC_RELAXED,
                         __HIP_MEMORY_SCOPE_AGENT);
    }

    if (t == TT - 1) break;

    __syncthreads();  // S2: gather(t) done, h stores drained
    if (tid == 0)
      __hip_atomic_store(&grpf[n], (unsigned)(t + 1), __ATOMIC_RELAXED,
                         __HIP_MEMORY_SCOPE_AGENT);

    // ---- shadow: x fragments + x-part MFMA for t+1 -----------------------
    ++t;
    xload(TT - 1 - t);
    xmfma();
  }
}

// ---- out = h_final @ W_out^T + b_out; h read from frag layout (sc1) --------
__global__ __launch_bounds__(256) void out_proj(const unsigned short* __restrict__ hfr,
                                                const float* __restrict__ Wout,
                                                const float* __restrict__ bout,
                                                float* __restrict__ out) {
  __shared__ float hs[HH];
  int b = blockIdx.x;
  int tid = threadIdx.x;
  const unsigned short* hb = hfr + (size_t)(b >> 5) * 32768;  // slot 0
  for (int kc = tid; kc < 128; kc += 256) {
    const u64* p = (const u64*)(hb + ((size_t)kc * 32 + (b & 31)) * 8);
    u64 lo = __hip_atomic_load(p, __ATOMIC_RELAXED, __HIP_MEMORY_SCOPE_AGENT);
    u64 hi = __hip_atomic_load(p + 1, __ATOMIC_RELAXED, __HIP_MEMORY_SCOPE_AGENT);
#pragma unroll
    for (int j = 0; j < 4; ++j) {
      hs[kc * 8 + j] = bf2f((unsigned short)(lo >> (16 * j)));
      hs[kc * 8 + 4 + j] = bf2f((unsigned short)(hi >> (16 * j)));
    }
  }
  __syncthreads();
  const float* wr = Wout + (size_t)tid * HH;
  float acc = bout[tid];
#pragma unroll 4
  for (int k = 0; k < HH; k += 4) {
    float4 wv = *(const float4*)(wr + k);
    acc += hs[k] * wv.x + hs[k + 1] * wv.y + hs[k + 2] * wv.z + hs[k + 3] * wv.w;
  }
  out[(size_t)b * OUTD + tid] = acc;
}

extern "C" void kernel_launch(void* const* d_in, const int* in_sizes, int n_in,
                              void* d_out, int out_size, void* d_ws, size_t ws_size,
                              hipStream_t stream) {
  const float* x    = (const float*)d_in[0];
  const float* Wih  = (const float*)d_in[1];
  const float* Whh  = (const float*)d_in[2];
  const float* bih  = (const float*)d_in[3];
  const float* bhh  = (const float*)d_in[4];
  const float* Wout = (const float*)d_in[5];
  const float* bout = (const float*)d_in[6];
  float* out = (float*)d_out;

  uint8_t* w = (uint8_t*)d_ws;
  unsigned short* Wc    = (unsigned short*)(w);             // 12,582,912 B
  unsigned short* hfr   = (unsigned short*)(w + 12582912);  // 4 slots x 262,144 B
  unsigned int*   flags = (unsigned int*)(w + 13631488);    // 1,024 B

  hipMemsetAsync(hfr, 0, 262144, stream);   // slot 0 = h(0) = 0
  hipMemsetAsync(flags, 0, 1024, stream);
  prep_wcat<<<1024, 256, 0, stream>>>(Wih, Whh, Wc);

  void* args[] = {(void*)&x, (void*)&Wc, (void*)&bih, (void*)&bhh,
                  (void*)&hfr, (void*)&flags};
  hipLaunchCooperativeKernel((const void*)lstm_persist, dim3(NWG), dim3(NTHR),
                             args, 0, stream);

  // h(512) lives in ring slot 512&3 = 0
  out_proj<<<BB, 256, 0, stream>>>(hfr, Wout, bout, out);
}